// Round 8
// baseline (193.919 us; speedup 1.0000x reference)
//
#include <hip/hip_runtime.h>

typedef unsigned short u16;
typedef unsigned int u32;
typedef __bf16 bf16x8 __attribute__((ext_vector_type(8)));
typedef u16 u16x8 __attribute__((ext_vector_type(8)));
typedef float f32x4 __attribute__((ext_vector_type(4)));

__device__ __forceinline__ u16 f2bf(float f) {
  u32 u = __float_as_uint(f);
  u32 r = (u + 0x7FFFu + ((u >> 16) & 1u)) >> 16;  // RNE
  return (u16)r;
}

// ---------------- kernel 0: cast x fp32 -> bf16 A[4608][512] ----------------
__global__ void k_cast(const float* __restrict__ x, u16* __restrict__ A) {
  int t = blockIdx.x * 256 + threadIdx.x;
  const float4* xp = (const float4*)x + (size_t)t * 2;
  float4 v0 = xp[0], v1 = xp[1];
  u16x8 r;
  r[0] = f2bf(v0.x); r[1] = f2bf(v0.y); r[2] = f2bf(v0.z); r[3] = f2bf(v0.w);
  r[4] = f2bf(v1.x); r[5] = f2bf(v1.y); r[6] = f2bf(v1.z); r[7] = f2bf(v1.w);
  *(u16x8*)(A + (size_t)t * 8) = r;
}

// ------- kernel 1: C = A*A^T with fused max over p (col groups of 9) -------
// R7: LDS-free direct-load GEMM. One wave per block (grid 72x32), wave-tile
// 64x144, acc[4][9]. Fragments loaded straight from global (each dwordx4 =
// 16 rows x 64B = fully coalesced); compiler emits fine-grained vmcnt waits;
// NO barriers in the K-loop. 8 blocks/CU interleave latency. Old R4 staged
// version: 2 barrier-drains/iter x 8 iters at 2 blocks/CU -> MfmaUtil 14%,
// 55 us. LDS only for the block-private max-epilogue slab.
__global__ __launch_bounds__(64, 2) void k_gemm_smax(const u16* __restrict__ A,
                                                     float* __restrict__ Smax) {
  __shared__ float epi[16 * 148];  // 9472 B
  const int rb = blockIdx.x, cb = blockIdx.y;
  const int rowBase = rb * 64, colBase = cb * 144;
  const int lane = threadIdx.x;
  const int lrow = lane & 15, lk = lane >> 4;

  const u16* Ap = A + (size_t)(rowBase + lrow) * 512 + lk * 8;
  const u16* Bp = A + (size_t)(colBase + lrow) * 512 + lk * 8;

  f32x4 acc[4][9];
#pragma unroll
  for (int rt = 0; rt < 4; ++rt)
#pragma unroll
    for (int ct = 0; ct < 9; ++ct) { f32x4 z = {0.f, 0.f, 0.f, 0.f}; acc[rt][ct] = z; }

#pragma unroll 1
  for (int k0 = 0; k0 < 512; k0 += 32) {
    bf16x8 af[4], bf[9];
#pragma unroll
    for (int rt = 0; rt < 4; ++rt)
      af[rt] = *(const bf16x8*)(Ap + (size_t)rt * 16 * 512 + k0);
#pragma unroll
    for (int ct = 0; ct < 9; ++ct)
      bf[ct] = *(const bf16x8*)(Bp + (size_t)ct * 16 * 512 + k0);
#pragma unroll
    for (int rt = 0; rt < 4; ++rt)
#pragma unroll
      for (int ct = 0; ct < 9; ++ct)
        acc[rt][ct] = __builtin_amdgcn_mfma_f32_16x16x32_bf16(af[rt], bf[ct],
                                                              acc[rt][ct], 0, 0, 0);
  }

  // epilogue: C/D layout col=lane&15, row=(lane>>4)*4+reg [measured];
  // per rt: dump 16x144 tile to LDS, max over col-groups of 9.
#pragma unroll
  for (int rt = 0; rt < 4; ++rt) {
    __syncthreads();
#pragma unroll
    for (int ct = 0; ct < 9; ++ct)
#pragma unroll
      for (int r = 0; r < 4; ++r)
        epi[(lk * 4 + r) * 148 + ct * 16 + lrow] = acc[rt][ct][r];
    __syncthreads();
#pragma unroll
    for (int q = 0; q < 4; ++q) {
      int o = lane + 64 * q;  // 16 rows x 16 groups
      int row = o >> 4, g = o & 15;
      const float* p = epi + row * 148 + g * 9;
      float m = p[0];
#pragma unroll
      for (int t = 1; t < 9; ++t) m = fmaxf(m, p[t]);
      Smax[(size_t)(rowBase + rt * 16 + row) * 512 + cb * 16 + g] = m;
    }
  }
}

// ---------- kernel 2: mean over o (row groups of 9) -> sim[64][64][64] ------
__global__ void k_reduce_o(const float* __restrict__ Smax, float* __restrict__ sim) {
  int idx = blockIdx.x * 256 + threadIdx.x;
  int j = idx & 63, i = (idx >> 6) & 63, b = (idx >> 12) & 7, a = idx >> 15;
  const float* p = Smax + (size_t)((a * 64 + i) * 9) * 512 + b * 64 + j;
  float s = p[0];
#pragma unroll
  for (int o = 1; o < 9; ++o) s += p[o * 512];
  sim[idx] = s * (1.f / 9.f);
}

// ---------- kernel W: repack conv weights to [tap][oc][ic] bf16 -------------
__global__ void k_wpack(const float* __restrict__ w2, const float* __restrict__ w3,
                        u16* __restrict__ p2, u16* __restrict__ p3) {
  int i = blockIdx.x * 256 + threadIdx.x;  // 73728 threads
  if (i < 18432) {
    int t = i >> 11, oc = (i >> 5) & 63, ic = i & 31;
    p2[i] = f2bf(w2[(oc * 32 + ic) * 9 + t]);
  }
  {
    int t = i >> 13, oc = (i >> 6) & 127, ic = i & 63;
    p3[i] = f2bf(w3[(oc * 64 + ic) * 9 + t]);
  }
}

// ---------- kernel 3: conv1 (1->32) + ReLU + maxpool2, channels-last bf16 ---
__global__ __launch_bounds__(256) void k_conv1pool(const float* __restrict__ sim,
                                                   const float* __restrict__ w1,
                                                   const float* __restrict__ b1,
                                                   u16* __restrict__ h1) {
  __shared__ float tin[4096];
  const int pair = blockIdx.x, ocg = blockIdx.y, tid = threadIdx.x;
  const float4* src = (const float4*)(sim + (size_t)pair * 4096);
  for (int i = tid; i < 1024; i += 256) ((float4*)tin)[i] = src[i];
  __syncthreads();
  float wv[8][9], bs[8];
#pragma unroll
  for (int o = 0; o < 8; ++o) {
#pragma unroll
    for (int q = 0; q < 9; ++q) wv[o][q] = w1[(ocg * 8 + o) * 9 + q];
    bs[o] = b1[ocg * 8 + o];
  }
  for (int pp = tid; pp < 1024; pp += 256) {
    int py = pp >> 5, px = pp & 31;
    float m[8];
#pragma unroll
    for (int o = 0; o < 8; ++o) m[o] = 0.f;
#pragma unroll
    for (int dy = 0; dy < 2; ++dy)
#pragma unroll
      for (int dx = 0; dx < 2; ++dx) {
        float s[8];
#pragma unroll
        for (int o = 0; o < 8; ++o) s[o] = bs[o];
        int yy = py * 2 + dy, xx0 = px * 2 + dx;
#pragma unroll
        for (int ky = 0; ky < 3; ++ky) {
          int y = yy + ky - 1;
          if ((unsigned)y < 64u) {
#pragma unroll
            for (int kx = 0; kx < 3; ++kx) {
              int x = xx0 + kx - 1;
              if ((unsigned)x < 64u) {
                float v = tin[y * 64 + x];
#pragma unroll
                for (int o = 0; o < 8; ++o) s[o] += wv[o][ky * 3 + kx] * v;
              }
            }
          }
        }
#pragma unroll
        for (int o = 0; o < 8; ++o) m[o] = fmaxf(m[o], fmaxf(s[o], 0.f));
      }
    u16x8 r;
#pragma unroll
    for (int o = 0; o < 8; ++o) r[o] = f2bf(m[o]);
    *(u16x8*)&h1[(((size_t)pair * 32 + py) * 32 + px) * 32 + ocg * 8] = r;
  }
}

// ---------- kernel 4: conv2 MFMA (32->64) + ReLU + maxpool2 -----------------
__global__ __launch_bounds__(256) void k_conv2pool(const u16* __restrict__ h1,
                                                   const u16* __restrict__ wp2,
                                                   const float* __restrict__ b2,
                                                   u16* __restrict__ h2) {
  __shared__ u16 tile[18 * 34 * 40];  // 48960 B
  const int pair = blockIdx.x, yh = blockIdx.y, tid = threadIdx.x;
  const int wave = tid >> 6, lane = tid & 63, l15 = lane & 15, quad = lane >> 4;
  u16x8 z8 = {0, 0, 0, 0, 0, 0, 0, 0};
  for (int i = tid; i < 3060; i += 256) ((u16x8*)tile)[i] = z8;
  __syncthreads();
  for (int f = tid; f < 1152; f += 256) {
    int i = f >> 6, rem = f & 63, px = rem >> 1, half = rem & 1;
    int gr = yh * 16 - 1 + i;
    if ((unsigned)gr < 32u)
      *(u16x8*)&tile[(i * 34 + 1 + px) * 40 + half * 16] =
          *(const u16x8*)&h1[(((size_t)pair * 32 + gr) * 32 + px) * 32 + half * 16];
  }
  __syncthreads();

  f32x4 acc[8][4];
#pragma unroll
  for (int m = 0; m < 8; ++m)
#pragma unroll
    for (int n = 0; n < 4; ++n) { f32x4 z = {0.f, 0.f, 0.f, 0.f}; acc[m][n] = z; }

  for (int t = 0; t < 9; ++t) {
    int ky = t / 3, kx = t % 3;
    bf16x8 wf[4];
#pragma unroll
    for (int nt = 0; nt < 4; ++nt)
      wf[nt] = *(const bf16x8*)&wp2[((t * 64 + nt * 16 + l15) << 5) + quad * 8];
#pragma unroll
    for (int rr = 0; rr < 4; ++rr)
#pragma unroll
      for (int xh = 0; xh < 2; ++xh) {
        int lr = wave * 4 + rr;
        bf16x8 af = *(const bf16x8*)&tile[((lr + ky) * 34 + xh * 16 + l15 + kx) * 40 +
                                          quad * 8];
#pragma unroll
        for (int nt = 0; nt < 4; ++nt)
          acc[rr * 2 + xh][nt] =
              __builtin_amdgcn_mfma_f32_16x16x32_bf16(af, wf[nt], acc[rr * 2 + xh][nt],
                                                      0, 0, 0);
      }
  }

  float bv[4];
#pragma unroll
  for (int nt = 0; nt < 4; ++nt) bv[nt] = b2[nt * 16 + l15];
#pragma unroll
  for (int rp = 0; rp < 2; ++rp)
#pragma unroll
    for (int xh = 0; xh < 2; ++xh) {
      int py = yh * 8 + wave * 2 + rp;
      int px0 = xh * 8 + quad * 2;
#pragma unroll
      for (int nt = 0; nt < 4; ++nt) {
        f32x4 va = acc[(rp * 2) * 2 + xh][nt], vb = acc[(rp * 2 + 1) * 2 + xh][nt];
        float p0 = fmaxf(fmaxf(fmaxf(va[0], va[1]), fmaxf(vb[0], vb[1])) + bv[nt], 0.f);
        float p1 = fmaxf(fmaxf(fmaxf(va[2], va[3]), fmaxf(vb[2], vb[3])) + bv[nt], 0.f);
        size_t base = (((size_t)pair * 16 + py) * 16 + px0) * 64 + nt * 16 + l15;
        h2[base] = f2bf(p0);
        h2[base + 64] = f2bf(p1);
      }
    }
}

// ---------- kernel 5: conv3 MFMA (64->128) + ReLU ---------------------------
__global__ __launch_bounds__(256) void k_conv3(const u16* __restrict__ h2,
                                               const u16* __restrict__ wp3,
                                               const float* __restrict__ b3,
                                               float* __restrict__ h3) {
  __shared__ u16 tile[18 * 18 * 72];  // 46656 B
  const int pair = blockIdx.x, oh = blockIdx.y, tid = threadIdx.x;
  const int wave = tid >> 6, lane = tid & 63, l15 = lane & 15, quad = lane >> 4;
  u16x8 z8 = {0, 0, 0, 0, 0, 0, 0, 0};
  for (int i = tid; i < 2916; i += 256) ((u16x8*)tile)[i] = z8;
  __syncthreads();
  for (int f = tid; f < 2048; f += 256) {
    int row = f >> 7, rem = f & 127, px = rem >> 3, seg = rem & 7;
    *(u16x8*)&tile[((row + 1) * 18 + px + 1) * 72 + seg * 8] =
        *(const u16x8*)&h2[(((size_t)pair * 16 + row) * 16 + px) * 64 + seg * 8];
  }
  __syncthreads();

  f32x4 acc[4][4];
#pragma unroll
  for (int m = 0; m < 4; ++m)
#pragma unroll
    for (int n = 0; n < 4; ++n) { f32x4 z = {0.f, 0.f, 0.f, 0.f}; acc[m][n] = z; }

  for (int t = 0; t < 9; ++t) {
    int ky = t / 3, kx = t % 3;
#pragma unroll
    for (int s = 0; s < 2; ++s) {
      bf16x8 wf[4];
#pragma unroll
      for (int nt = 0; nt < 4; ++nt)
        wf[nt] = *(const bf16x8*)&wp3[((t * 128 + oh * 64 + nt * 16 + l15) << 6) +
                                      s * 32 + quad * 8];
#pragma unroll
      for (int yt = 0; yt < 4; ++yt) {
        int y = wave * 4 + yt;
        bf16x8 af = *(const bf16x8*)&tile[((y + ky) * 18 + l15 + kx) * 72 + s * 32 +
                                          quad * 8];
#pragma unroll
        for (int nt = 0; nt < 4; ++nt)
          acc[yt][nt] = __builtin_amdgcn_mfma_f32_16x16x32_bf16(af, wf[nt],
                                                                acc[yt][nt], 0, 0, 0);
      }
    }
  }

  float bv[4];
#pragma unroll
  for (int nt = 0; nt < 4; ++nt) bv[nt] = b3[oh * 64 + nt * 16 + l15];
#pragma unroll
  for (int yt = 0; yt < 4; ++yt)
#pragma unroll
    for (int nt = 0; nt < 4; ++nt)
#pragma unroll
      for (int r = 0; r < 4; ++r) {
        int px = (wave * 4 + yt) * 16 + quad * 4 + r;
        h3[((size_t)pair * 256 + px) * 128 + oh * 64 + nt * 16 + l15] =
            fmaxf(acc[yt][nt][r] + bv[nt], 0.f);
      }
}

// ---------- kernel 6: zero the output (loss accumulator) --------------------
__global__ void k_zero(float* __restrict__ out) {
  if (threadIdx.x < 65) out[threadIdx.x] = 0.f;
}

// ---------- kernel 7: conv4 1x1 (128->1) + loss + hardtanh + chamfer --------
__global__ __launch_bounds__(256) void k_conv4(const float* __restrict__ h3,
                                               const float* __restrict__ w4,
                                               const float* __restrict__ b4,
                                               float* __restrict__ out) {
  __shared__ float ws4[128];
  __shared__ float rowmax[16];
  __shared__ float lsum[4];
  const int pair = blockIdx.x, tid = threadIdx.x;
  if (tid < 128) ws4[tid] = w4[tid];
  __syncthreads();
  float h = b4[0];
  const float4* p = (const float4*)(h3 + ((size_t)pair * 256 + tid) * 128);
#pragma unroll 8
  for (int i = 0; i < 32; ++i) {
    float4 v = p[i];
    h += v.x * ws4[i * 4] + v.y * ws4[i * 4 + 1] + v.z * ws4[i * 4 + 2] +
         v.w * ws4[i * 4 + 3];
  }
  float loss = fmaxf(-(h + 1.f), 0.f) + fmaxf(h - 1.f, 0.f);
  float sc = fminf(fmaxf(h, -1.f), 1.f) * 0.5f + 0.5f;
#pragma unroll
  for (int off = 8; off >= 1; off >>= 1) sc = fmaxf(sc, __shfl_xor(sc, off, 16));
#pragma unroll
  for (int off = 32; off >= 1; off >>= 1) loss += __shfl_xor(loss, off, 64);
  if ((tid & 15) == 0) rowmax[tid >> 4] = sc;
  if ((tid & 63) == 0) lsum[tid >> 6] = loss;
  __syncthreads();
  if (tid == 0) {
    float mean = 0.f;
#pragma unroll
    for (int i = 0; i < 16; ++i) mean += rowmax[i];
    out[pair] = mean * (1.f / 16.f);
    atomicAdd(out + 64, lsum[0] + lsum[1] + lsum[2] + lsum[3]);
  }
}

extern "C" void kernel_launch(void* const* d_in, const int* in_sizes, int n_in,
                              void* d_out, int out_size, void* d_ws, size_t ws_size,
                              hipStream_t stream) {
  (void)in_sizes; (void)n_in; (void)out_size; (void)ws_size;
  const float* x  = (const float*)d_in[0];
  const float* w1 = (const float*)d_in[1];
  const float* b1 = (const float*)d_in[2];
  const float* w2 = (const float*)d_in[3];
  const float* b2 = (const float*)d_in[4];
  const float* w3 = (const float*)d_in[5];
  const float* b3 = (const float*)d_in[6];
  const float* w4 = (const float*)d_in[7];
  const float* b4 = (const float*)d_in[8];
  float* out = (float*)d_out;

  char* ws = (char*)d_ws;
  u16*   Abf  = (u16*)ws;                          // 4,718,592 B
  float* Smax = (float*)(ws + 4718592);            // 9,437,184 B
  float* sim  = (float*)(ws + 14155776);           // 1,048,576 B
  u16*   h1   = (u16*)(ws + 15204352);             // 4,194,304 B (bf16 chan-last)
  u16*   h2   = (u16*)(ws + 19398656);             // 2,097,152 B (bf16 chan-last)
  float* h3   = (float*)(ws + 21495808);           // 8,388,608 B (fp32 chan-last)
  u16*   wp2  = (u16*)(ws + 29884416);             //    36,864 B
  u16*   wp3  = (u16*)(ws + 29921280);             //   147,456 B (end ~30.1 MB)

  k_cast<<<1152, 256, 0, stream>>>(x, Abf);
  k_gemm_smax<<<dim3(72, 32), 64, 0, stream>>>(Abf, Smax);
  k_reduce_o<<<1024, 256, 0, stream>>>(Smax, sim);
  k_wpack<<<288, 256, 0, stream>>>(w2, w3, wp2, wp3);
  k_conv1pool<<<dim3(64, 4), 256, 0, stream>>>(sim, w1, b1, h1);
  k_conv2pool<<<dim3(64, 2), 256, 0, stream>>>(h1, wp2, b2, h2);
  k_conv3<<<dim3(64, 2), 256, 0, stream>>>(h2, wp3, b3, h3);
  k_zero<<<1, 128, 0, stream>>>(out);
  k_conv4<<<64, 256, 0, stream>>>(h3, w4, b4, out);
}